// Round 3
// baseline (863.344 us; speedup 1.0000x reference)
//
#include <hip/hip_runtime.h>
#include <math.h>

// Problem constants (from reference)
#define DD   40
#define HWsz 1600        // H*W
#define NVOX 64000       // D*H*W
#define NB   2
#define KP   2048
#define KT   40960
#define EPSV 2.0f
#define TC   1024        // true-list chunk per block (grid.x = KT/TC = 40)
#define PCH  256         // preds per block (grid.y = KP/PCH = 8)
#define INF_I 0x7fffffff

// Workspace layout (~360 KB). Poisoned 0xAA before every launch -> init_k
// re-initializes everything we read.
struct Ws {
  int   pcount[NB];
  int   tcount[NB];
  float sum;
  int   pad;
  int   mind2[NB][KP];   // per-pred min squared distance (int, exact)
  int   pidx[NB][KP];    // packed pred coords (z<<12 | y<<6 | x)
  int   tpk[NB][KT];     // packed true coords
};

__global__ void init_k(Ws* ws) {
  int gid = blockIdx.x * blockDim.x + threadIdx.x;
  if (gid == 0) {
    ws->pcount[0] = 0; ws->pcount[1] = 0;
    ws->tcount[0] = 0; ws->tcount[1] = 0;
    ws->sum = 0.0f;
  }
  if (gid < NB * KP) ((int*)ws->mind2)[gid] = INF_I;
}

__global__ void compact_k(const float* __restrict__ inp,
                          const float* __restrict__ tgt,
                          Ws* __restrict__ ws) {
  int gid = blockIdx.x * blockDim.x + threadIdx.x;
  if (gid >= NB * NVOX) return;
  int b = gid / NVOX;
  int v = gid - b * NVOX;
  int z = v / HWsz;
  int r = v - z * HWsz;
  int y = r / DD;
  int x = r - y * DD;
  int pk = (z << 12) | (y << 6) | x;
  // Counts never exceed capacity in practice (15sigma+ margin), so order of
  // atomic compaction is irrelevant to the final sum.
  if (inp[gid] > EPSV) {
    int pos = atomicAdd(&ws->pcount[b], 1);
    if (pos < KP) ws->pidx[b][pos] = pk;
  }
  if (tgt[gid] > 0.0f) {
    int pos = atomicAdd(&ws->tcount[b], 1);
    if (pos < KT) ws->tpk[b][pos] = pk;
  }
}

// One thread = one pred point; block scans a TC-sized chunk of the true list.
// True-coord loads are wave-uniform -> scalar loads; unpack is SALU.
__global__ void nn_k(Ws* __restrict__ ws) {
  int b     = blockIdx.z;
  int pbase = blockIdx.y * PCH;
  int tbase = blockIdx.x * TC;
  int pc = min(ws->pcount[b], KP);
  int tc = min(ws->tcount[b], KT);
  if (pbase >= pc || tbase >= tc) return;

  int p = pbase + (int)threadIdx.x;
  bool valid = p < pc;
  int pk = valid ? ws->pidx[b][p] : 0;
  int px = pk & 63, py = (pk >> 6) & 63, pz = pk >> 12;

  int tend = min(tbase + TC, tc);
  int best = INF_I;
  const int* __restrict__ tarr = ws->tpk[b];
  #pragma unroll 4
  for (int j = tbase; j < tend; ++j) {
    int t  = tarr[j];                 // uniform -> s_load
    int dx = px - (t & 63);
    int dy = py - ((t >> 6) & 63);
    int dz = pz - (t >> 12);
    int d2 = dx * dx + dy * dy + dz * dz;
    best = min(best, d2);
  }
  if (valid) atomicMin(&ws->mind2[b][p], best);
}

__global__ void collect_k(Ws* __restrict__ ws) {
  int gid = blockIdx.x * blockDim.x + threadIdx.x;   // [0, NB*KP)
  int b = gid / KP;
  int p = gid - b * KP;
  int pc = min(ws->pcount[b], KP);
  int tc = min(ws->tcount[b], KT);
  float dist = 0.0f;
  // Reference: if no true points exist, per-pred distance is 0 but the pred
  // still counts toward the mean's denominator.
  if (p < pc && tc > 0) dist = sqrtf((float)ws->mind2[b][p]);
  // wave-64 shuffle reduction, then one atomic per wave
  for (int o = 32; o > 0; o >>= 1) dist += __shfl_down(dist, o, 64);
  if ((threadIdx.x & 63) == 0 && dist != 0.0f) atomicAdd(&ws->sum, dist);
}

__global__ void finalize_k(const Ws* __restrict__ ws, float* __restrict__ out) {
  int cnt = min(ws->pcount[0], KP) + min(ws->pcount[1], KP);
  out[0] = (cnt > 0) ? (ws->sum / (float)cnt) : 0.0f;
}

extern "C" void kernel_launch(void* const* d_in, const int* in_sizes, int n_in,
                              void* d_out, int out_size, void* d_ws, size_t ws_size,
                              hipStream_t stream) {
  const float* inp = (const float*)d_in[0];
  const float* tgt = (const float*)d_in[1];
  float* out = (float*)d_out;
  Ws* ws = (Ws*)d_ws;

  hipLaunchKernelGGL(init_k, dim3((NB * KP + 255) / 256), dim3(256), 0, stream, ws);
  hipLaunchKernelGGL(compact_k, dim3((NB * NVOX + 255) / 256), dim3(256), 0, stream,
                     inp, tgt, ws);
  hipLaunchKernelGGL(nn_k, dim3(KT / TC, KP / PCH, NB), dim3(PCH), 0, stream, ws);
  hipLaunchKernelGGL(collect_k, dim3((NB * KP) / 256), dim3(256), 0, stream, ws);
  hipLaunchKernelGGL(finalize_k, dim3(1), dim3(1), 0, stream, ws, out);
}

// Round 4
// 115.791 us; speedup vs baseline: 7.4561x; 7.4561x over previous
//
#include <hip/hip_runtime.h>
#include <math.h>

// Problem constants (from reference)
#define DD   40
#define HWsz 1600        // H*W
#define NVOX 64000       // D*H*W
#define NB   2
#define KP   2048
#define KT   40960
#define EPSV 2.0f
#define TC   1024        // true-list chunk per block (grid.x = KT/TC = 40)
#define PCH  256         // preds per block (grid.y = KP/PCH = 8)
#define INF_I 0x7fffffff

// Workspace layout (~360 KB). Poisoned 0xAA before every launch -> init_k
// re-initializes everything we read.
struct Ws {
  int   pcount[NB];
  int   tcount[NB];
  float sum;
  int   pad;
  int   mind2[NB][KP];   // per-pred min squared distance (int, exact)
  int   pidx[NB][KP];    // packed pred coords (z<<12 | y<<6 | x)
  int   tpk[NB][KT];     // packed true coords
};

__global__ void init_k(Ws* ws) {
  int gid = blockIdx.x * blockDim.x + threadIdx.x;
  if (gid == 0) {
    ws->pcount[0] = 0; ws->pcount[1] = 0;
    ws->tcount[0] = 0; ws->tcount[1] = 0;
    ws->sum = 0.0f;
  }
  if (gid < NB * KP) ((int*)ws->mind2)[gid] = INF_I;
}

// Two-level compaction: per-wave ballot -> per-block LDS sum -> ONE global
// atomicAdd per block per counter. R3 showed 64K same-address lane-atomics
// (atomicAdd-with-return defeats the compiler's per-wave coalescing) cost
// 760 us; this cuts global atomics 256x (128K -> 500 per counter pair).
__global__ void compact_k(const float* __restrict__ inp,
                          const float* __restrict__ tgt,
                          Ws* __restrict__ ws) {
  int gid = blockIdx.x * blockDim.x + threadIdx.x;   // grid is exact fit
  int b = gid / NVOX;    // block-uniform: NVOX % 256 == 0
  int v = gid - b * NVOX;
  int z = v / HWsz;
  int r = v - z * HWsz;
  int y = r / DD;
  int x = r - y * DD;
  int pk = (z << 12) | (y << 6) | x;

  bool pp = inp[gid] > EPSV;
  bool tp = tgt[gid] > 0.0f;
  unsigned long long pm = __ballot(pp);
  unsigned long long tm = __ballot(tp);
  int lane = threadIdx.x & 63;
  int wid  = threadIdx.x >> 6;     // 4 waves/block

  __shared__ int wp[4], wt[4];
  __shared__ int pbase, tbase;
  if (lane == 0) { wp[wid] = __popcll(pm); wt[wid] = __popcll(tm); }
  __syncthreads();
  if (threadIdx.x == 0) {
    int sp = wp[0] + wp[1] + wp[2] + wp[3];
    int st = wt[0] + wt[1] + wt[2] + wt[3];
    pbase = atomicAdd(&ws->pcount[b], sp);
    tbase = atomicAdd(&ws->tcount[b], st);
  }
  __syncthreads();

  int wpoff = 0, wtoff = 0;
  #pragma unroll
  for (int i = 0; i < 4; ++i) {
    if (i < wid) { wpoff += wp[i]; wtoff += wt[i]; }
  }
  unsigned long long below = (1ull << lane) - 1ull;
  if (pp) {
    int pos = pbase + wpoff + __popcll(pm & below);
    if (pos < KP) ws->pidx[b][pos] = pk;
  }
  if (tp) {
    int pos = tbase + wtoff + __popcll(tm & below);
    if (pos < KT) ws->tpk[b][pos] = pk;
  }
}

// One thread = one pred point; block scans a TC-sized chunk of the true list.
// True-coord loads are wave-uniform -> scalar loads; unpack is SALU.
__global__ void nn_k(Ws* __restrict__ ws) {
  int b     = blockIdx.z;
  int pbase = blockIdx.y * PCH;
  int tbase = blockIdx.x * TC;
  int pc = min(ws->pcount[b], KP);
  int tc = min(ws->tcount[b], KT);
  if (pbase >= pc || tbase >= tc) return;

  int p = pbase + (int)threadIdx.x;
  bool valid = p < pc;
  int pk = valid ? ws->pidx[b][p] : 0;
  int px = pk & 63, py = (pk >> 6) & 63, pz = pk >> 12;

  int tend = min(tbase + TC, tc);
  int best = INF_I;
  const int* __restrict__ tarr = ws->tpk[b];
  #pragma unroll 4
  for (int j = tbase; j < tend; ++j) {
    int t  = tarr[j];                 // uniform -> s_load
    int dx = px - (t & 63);
    int dy = py - ((t >> 6) & 63);
    int dz = pz - (t >> 12);
    int d2 = dx * dx + dy * dy + dz * dz;
    best = min(best, d2);
  }
  if (valid) atomicMin(&ws->mind2[b][p], best);
}

__global__ void collect_k(Ws* __restrict__ ws) {
  int gid = blockIdx.x * blockDim.x + threadIdx.x;   // [0, NB*KP)
  int b = gid / KP;
  int p = gid - b * KP;
  int pc = min(ws->pcount[b], KP);
  int tc = min(ws->tcount[b], KT);
  float dist = 0.0f;
  // Reference: if no true points exist, per-pred distance is 0 but the pred
  // still counts toward the mean's denominator.
  if (p < pc && tc > 0) dist = sqrtf((float)ws->mind2[b][p]);
  // wave-64 shuffle reduction, then one atomic per wave
  for (int o = 32; o > 0; o >>= 1) dist += __shfl_down(dist, o, 64);
  if ((threadIdx.x & 63) == 0 && dist != 0.0f) atomicAdd(&ws->sum, dist);
}

__global__ void finalize_k(const Ws* __restrict__ ws, float* __restrict__ out) {
  int cnt = min(ws->pcount[0], KP) + min(ws->pcount[1], KP);
  out[0] = (cnt > 0) ? (ws->sum / (float)cnt) : 0.0f;
}

extern "C" void kernel_launch(void* const* d_in, const int* in_sizes, int n_in,
                              void* d_out, int out_size, void* d_ws, size_t ws_size,
                              hipStream_t stream) {
  const float* inp = (const float*)d_in[0];
  const float* tgt = (const float*)d_in[1];
  float* out = (float*)d_out;
  Ws* ws = (Ws*)d_ws;

  hipLaunchKernelGGL(init_k, dim3((NB * KP + 255) / 256), dim3(256), 0, stream, ws);
  hipLaunchKernelGGL(compact_k, dim3(NB * NVOX / 256), dim3(256), 0, stream,
                     inp, tgt, ws);
  hipLaunchKernelGGL(nn_k, dim3(KT / TC, KP / PCH, NB), dim3(PCH), 0, stream, ws);
  hipLaunchKernelGGL(collect_k, dim3((NB * KP) / 256), dim3(256), 0, stream, ws);
  hipLaunchKernelGGL(finalize_k, dim3(1), dim3(1), 0, stream, ws, out);
}

// Round 5
// 79.395 us; speedup vs baseline: 10.8740x; 1.4584x over previous
//
#include <hip/hip_runtime.h>
#include <math.h>

// Problem constants (from reference)
#define DDIM  40
#define HWsz  1600        // H*W
#define NVOX  64000       // D*H*W
#define NB    2
#define EPSV  2.0f
#define NWORD 1000        // uint64 mask words per batch (64000/64)
#define NBLK  (NB * NVOX / 256)   // 500 blocks for the voxel-parallel kernels
#define INF_I 0x7fffffff

// Workspace (~16 KB). Poisoned 0xAA before every launch; mask_k block 0
// zeroes sum/cnt/done (stream-ordered before nn_k reads them), and every
// tmask word is overwritten by exactly one wave.
struct Ws {
  unsigned long long tmask[NB * NWORD];  // true-voxel occupancy bitmask
  float sum;    // total 1-NN distance
  int   cnt;    // total pred count
  int   done;   // block completion counter for last-block finalize
};

// Build the true-occupancy bitmask: one ballot + one uint64 store per wave.
// No atomics, no compaction. gid>>6 == b*NWORD + (v>>6) since NVOX%64==0.
__global__ void mask_k(const float* __restrict__ tgt, Ws* __restrict__ ws) {
  int gid = blockIdx.x * blockDim.x + threadIdx.x;   // exact-fit grid
  if (gid == 0) { ws->sum = 0.0f; ws->cnt = 0; ws->done = 0; }
  unsigned long long m = __ballot(tgt[gid] > 0.0f);
  if ((threadIdx.x & 63) == 0) ws->tmask[gid >> 6] = m;
}

// One thread per voxel. Pred voxels do an expanding Chebyshev-shell search
// over the bitmask; prune when s^2 > best_d2 (exhaustive: Euclid d2 >= s^2
// on shell s). True density ~0.5 -> ~27 probes/pred vs 32000 brute-force.
// Then wave+LDS reduce, one atomicAdd per block, last block finalizes.
__global__ void nn_k(const float* __restrict__ inp, Ws* __restrict__ ws,
                     float* __restrict__ out) {
  int gid = blockIdx.x * blockDim.x + threadIdx.x;
  int b = gid / NVOX;          // block-uniform (NVOX % 256 == 0)
  int v = gid - b * NVOX;
  bool pred = inp[gid] > EPSV;

  float dist = 0.0f;
  if (pred) {
    int pz = v / HWsz;
    int r  = v - pz * HWsz;
    int py = r / DDIM;
    int px = r - py * DDIM;
    const unsigned long long* __restrict__ tm = ws->tmask + b * NWORD;
    int best = INF_I;
    for (int s = 0; s < DDIM; ++s) {
      if (s * s > best) break;           // no closer point possible
      for (int dz = -s; dz <= s; ++dz) {
        int zz = pz + dz;
        if ((unsigned)zz >= (unsigned)DDIM) continue;
        int edgez = (dz == -s) | (dz == s);
        for (int dy = -s; dy <= s; ++dy) {
          int yy = py + dy;
          if ((unsigned)yy >= (unsigned)DDIM) continue;
          // interior rows only need the two x-faces of the shell
          int stepx = (edgez | (dy == -s) | (dy == s)) ? 1 : 2 * s;
          for (int dx = -s; dx <= s; dx += stepx) {
            int xx = px + dx;
            if ((unsigned)xx >= (unsigned)DDIM) continue;
            int vv = zz * HWsz + yy * DDIM + xx;
            if ((tm[vv >> 6] >> (vv & 63)) & 1ull) {
              int d2 = dz * dz + dy * dy + dx * dx;  // exact int
              best = min(best, d2);
            }
          }
        }
      }
    }
    // Reference: no true points -> distance 0 (pred still counts in cnt).
    if (best != INF_I) dist = sqrtf((float)best);
  }

  // wave reduction (64 lanes)
  for (int o = 32; o > 0; o >>= 1) dist += __shfl_down(dist, o, 64);
  int wcount = __popcll(__ballot(pred));

  __shared__ float lsum[4];
  __shared__ int   lcnt[4];
  int lane = threadIdx.x & 63, wid = threadIdx.x >> 6;
  if (lane == 0) { lsum[wid] = dist; lcnt[wid] = wcount; }
  __syncthreads();
  if (threadIdx.x == 0) {
    float bs = lsum[0] + lsum[1] + lsum[2] + lsum[3];
    int   bc = lcnt[0] + lcnt[1] + lcnt[2] + lcnt[3];
    if (bs != 0.0f) atomicAdd(&ws->sum, bs);   // fire-and-forget, pipelines
    if (bc != 0)    atomicAdd(&ws->cnt, bc);
    __threadfence();                            // publish before done++
    int prev = atomicAdd(&ws->done, 1);
    if (prev == NBLK - 1) {
      // all 499 other blocks fenced before their done-increment; read via
      // device-scope atomic RMW to defeat any stale per-XCD caching
      float s = atomicAdd(&ws->sum, 0.0f);
      int   c = atomicAdd(&ws->cnt, 0);
      out[0] = (c > 0) ? s / (float)c : 0.0f;
    }
  }
}

extern "C" void kernel_launch(void* const* d_in, const int* in_sizes, int n_in,
                              void* d_out, int out_size, void* d_ws, size_t ws_size,
                              hipStream_t stream) {
  const float* inp = (const float*)d_in[0];
  const float* tgt = (const float*)d_in[1];
  float* out = (float*)d_out;
  Ws* ws = (Ws*)d_ws;

  hipLaunchKernelGGL(mask_k, dim3(NBLK), dim3(256), 0, stream, tgt, ws);
  hipLaunchKernelGGL(nn_k,   dim3(NBLK), dim3(256), 0, stream, inp, ws, out);
}

// Round 6
// 78.545 us; speedup vs baseline: 10.9917x; 1.0108x over previous
//
#include <hip/hip_runtime.h>
#include <math.h>

// Problem constants (from reference)
#define DDIM  40
#define HWsz  1600        // H*W
#define NVOX  64000       // D*H*W
#define NB    2
#define EPSV  2.0f
#define NBLK  (NB * NVOX / 256)   // 500 blocks
#define INF_I 0x7fffffff

// Workspace (12 bytes used). Poisoned 0xAA before every launch -> init_k
// zeroes the three words (stream-ordered before nn_k).
struct Ws {
  float sum;    // total 1-NN distance
  int   cnt;    // total pred count
  int   done;   // block completion counter for last-block finalize
};

__global__ void init_k(Ws* ws) {
  if (threadIdx.x == 0) { ws->sum = 0.0f; ws->cnt = 0; ws->done = 0; }
}

// Fused 1-NN: one thread per voxel, probing tgt>0 directly (no bitmask pass).
// s=0: self-hit fast path (~50% of preds). s=1: fully unrolled 26 independent
// predicated loads (single vmcnt drain, not 26 serial latencies). s>=2:
// general expanding-Chebyshev-shell loop, prune when s^2 > best (exhaustive:
// Euclid d2 >= s^2 on shell s; P(reaching s=2) ~ 2^-27 at density 0.5).
__global__ void nn_k(const float* __restrict__ inp,
                     const float* __restrict__ tgt,
                     Ws* __restrict__ ws, float* __restrict__ out) {
  int gid = blockIdx.x * blockDim.x + threadIdx.x;
  int b = gid / NVOX;          // block-uniform (NVOX % 256 == 0)
  int v = gid - b * NVOX;
  bool pred = inp[gid] > EPSV;

  float dist = 0.0f;
  if (pred && !(tgt[gid] > 0.0f)) {     // s=0 miss -> search
    int pz = v / HWsz;
    int r  = v - pz * HWsz;
    int py = r / DDIM;
    int px = r - py * DDIM;
    const float* __restrict__ tb = tgt + b * NVOX;
    int best = INF_I;

    // s=1 shell: 26 neighbors, unrolled, independent loads
    #pragma unroll
    for (int dz = -1; dz <= 1; ++dz)
      #pragma unroll
      for (int dy = -1; dy <= 1; ++dy)
        #pragma unroll
        for (int dx = -1; dx <= 1; ++dx) {
          if (dz == 0 && dy == 0 && dx == 0) continue;
          int zz = pz + dz, yy = py + dy, xx = px + dx;
          bool ok = (unsigned)zz < (unsigned)DDIM &&
                    (unsigned)yy < (unsigned)DDIM &&
                    (unsigned)xx < (unsigned)DDIM;
          if (ok && tb[zz * HWsz + yy * DDIM + xx] > 0.0f) {
            int d2 = dz * dz + dy * dy + dx * dx;
            best = min(best, d2);
          }
        }

    if (best == INF_I) {
      // residual general search (keeps exhaustive correctness)
      for (int s = 2; s < DDIM; ++s) {
        if ((long long)s * s > (long long)best) break;
        for (int dz = -s; dz <= s; ++dz) {
          int zz = pz + dz;
          if ((unsigned)zz >= (unsigned)DDIM) continue;
          int edgez = (dz == -s) | (dz == s);
          for (int dy = -s; dy <= s; ++dy) {
            int yy = py + dy;
            if ((unsigned)yy >= (unsigned)DDIM) continue;
            int stepx = (edgez | (dy == -s) | (dy == s)) ? 1 : 2 * s;
            for (int dx = -s; dx <= s; dx += stepx) {
              int xx = px + dx;
              if ((unsigned)xx >= (unsigned)DDIM) continue;
              if (tb[zz * HWsz + yy * DDIM + xx] > 0.0f) {
                int d2 = dz * dz + dy * dy + dx * dx;
                best = min(best, d2);
              }
            }
          }
        }
      }
    }
    // Reference: no true points anywhere -> distance 0 (pred still counted).
    if (best != INF_I) dist = sqrtf((float)best);
  }

  // wave reduction (64 lanes)
  for (int o = 32; o > 0; o >>= 1) dist += __shfl_down(dist, o, 64);
  int wcount = __popcll(__ballot(pred));

  __shared__ float lsum[4];
  __shared__ int   lcnt[4];
  int lane = threadIdx.x & 63, wid = threadIdx.x >> 6;
  if (lane == 0) { lsum[wid] = dist; lcnt[wid] = wcount; }
  __syncthreads();
  if (threadIdx.x == 0) {
    float bs = lsum[0] + lsum[1] + lsum[2] + lsum[3];
    int   bc = lcnt[0] + lcnt[1] + lcnt[2] + lcnt[3];
    if (bs != 0.0f) atomicAdd(&ws->sum, bs);
    if (bc != 0)    atomicAdd(&ws->cnt, bc);
    __threadfence();                            // publish before done++
    int prev = atomicAdd(&ws->done, 1);
    if (prev == NBLK - 1) {
      // all other blocks fenced before their done-increment; read via
      // device-scope atomic RMW to defeat stale per-XCD caching
      float s = atomicAdd(&ws->sum, 0.0f);
      int   c = atomicAdd(&ws->cnt, 0);
      out[0] = (c > 0) ? s / (float)c : 0.0f;
    }
  }
}

extern "C" void kernel_launch(void* const* d_in, const int* in_sizes, int n_in,
                              void* d_out, int out_size, void* d_ws, size_t ws_size,
                              hipStream_t stream) {
  const float* inp = (const float*)d_in[0];
  const float* tgt = (const float*)d_in[1];
  float* out = (float*)d_out;
  Ws* ws = (Ws*)d_ws;

  hipLaunchKernelGGL(init_k, dim3(1), dim3(64), 0, stream, ws);
  hipLaunchKernelGGL(nn_k,   dim3(NBLK), dim3(256), 0, stream, inp, tgt, ws, out);
}